// Round 4
// baseline (684.546 us; speedup 1.0000x reference)
//
#include <hip/hip_runtime.h>

#define CC 384
#define HW 3136            // 56*56
#define WIDTH 56
#define PLANE_ELEMS (CC*HW)  // 1204224
#define EPS 1e-5f

// bf16 x_pw for plane p lives in the 2nd half of plane p's f32 output slot:
// ushort index = p*6272 + 3136 + j   (slot = 12544 B = 6272 ushorts)
#define SLOT_U 6272
#define HALF_U 3136

typedef __attribute__((ext_vector_type(8))) short bf16x8;
typedef __attribute__((ext_vector_type(4))) float f32x4;

static __device__ __forceinline__ float bf2f(unsigned short u) {
  union { unsigned int i; float f; } x; x.i = ((unsigned int)u) << 16; return x.f;
}
static __device__ __forceinline__ unsigned short f2bf(float f) {
  union { float f; unsigned int i; } x; x.f = f;
  unsigned int r = x.i + 0x7fffu + ((x.i >> 16) & 1u);
  return (unsigned short)(r >> 16);
}

// ---------------------------------------------------------------------------
// Kernel A: y = W @ x (1x1 conv over channels, f32 in), BN, + residual ->
// x_pw (bf16) stashed into per-plane second-half slots of d_out.
// Tile: 64 spatial (M) x 64 out-channels (N), K=384 in 12 steps of 32.
// MFMA 16x16x32_bf16; f32 inputs converted to bf16 during LDS staging.
// ---------------------------------------------------------------------------
__global__ __launch_bounds__(256) void pw_gemm_bn_res(
    const float* __restrict__ xin,
    const float* __restrict__ wmat,
    const float* __restrict__ pwg, const float* __restrict__ pwb,
    const float* __restrict__ pwm, const float* __restrict__ pwv,
    unsigned short* __restrict__ xpw)   // = (ushort*)d_out
{
  __shared__ __align__(16) unsigned short Xt[64 * 40];  // [j][k], row padded to 40
  __shared__ __align__(16) unsigned short Wt[64 * 40];  // [n][k]
  __shared__ float scaleS[64];
  __shared__ float shiftS[64];

  const int tid = threadIdx.x;
  const int j0 = blockIdx.x * 64;   // spatial tile (3136 = 49*64)
  const int o0 = blockIdx.y * 64;   // out-channel tile (384 = 6*64)
  const int b  = blockIdx.z;
  const size_t bbase = (size_t)b * PLANE_ELEMS;

  if (tid < 64) {
    int o = o0 + tid;
    float s = pwg[o] * rsqrtf(pwv[o] + EPS);
    scaleS[tid] = s;
    shiftS[tid] = pwb[o] - pwm[o] * s;
  }

  f32x4 acc0 = {0.f,0.f,0.f,0.f}, acc1 = {0.f,0.f,0.f,0.f};
  f32x4 acc2 = {0.f,0.f,0.f,0.f}, acc3 = {0.f,0.f,0.f,0.f};

  const int lane = tid & 63;
  const int wv_  = tid >> 6;        // wave id 0..3 -> spatial sub-tile
  const int l15  = lane & 15;
  const int q    = lane >> 4;

  // staging index precompute
  const int skk  = tid >> 3;          // 0..31  X: k row
  const int sjj  = (tid & 7) << 3;    // 0..56  X: j col start (8 wide)
  const int sn   = tid >> 2;          // 0..63  W: n row
  const int skk0 = (tid & 3) << 3;    // 0..24  W: k start (8 wide)

  for (int kt = 0; kt < 12; ++kt) {
    const int c0 = kt * 32;
    __syncthreads();  // protect LDS from previous iteration's readers
    // stage X transposed: Xt[j][k] <- bf16(x[b][c0+k][j0+j])
    {
      const float* src = xin + bbase + (size_t)(c0 + skk) * HW + (j0 + sjj);
      float4 p0 = *((const float4*)src);
      float4 p1 = *((const float4*)(src + 4));
      Xt[(sjj + 0) * 40 + skk] = f2bf(p0.x);
      Xt[(sjj + 1) * 40 + skk] = f2bf(p0.y);
      Xt[(sjj + 2) * 40 + skk] = f2bf(p0.z);
      Xt[(sjj + 3) * 40 + skk] = f2bf(p0.w);
      Xt[(sjj + 4) * 40 + skk] = f2bf(p1.x);
      Xt[(sjj + 5) * 40 + skk] = f2bf(p1.y);
      Xt[(sjj + 6) * 40 + skk] = f2bf(p1.z);
      Xt[(sjj + 7) * 40 + skk] = f2bf(p1.w);
    }
    // stage W: Wt[n][k] <- bf16(pw_w[o0+n][c0+k])
    {
      const float* src = wmat + (size_t)(o0 + sn) * CC + (c0 + skk0);
      float4 p0 = *((const float4*)src);
      float4 p1 = *((const float4*)(src + 4));
      ushort4 u0, u1;
      u0.x = f2bf(p0.x); u0.y = f2bf(p0.y); u0.z = f2bf(p0.z); u0.w = f2bf(p0.w);
      u1.x = f2bf(p1.x); u1.y = f2bf(p1.y); u1.z = f2bf(p1.z); u1.w = f2bf(p1.w);
      *((ushort4*)&Wt[sn * 40 + skk0])     = u0;
      *((ushort4*)&Wt[sn * 40 + skk0 + 4]) = u1;
    }
    __syncthreads();

    bf16x8 a  = *((const bf16x8*)&Xt[(wv_ * 16 + l15) * 40 + q * 8]);
    bf16x8 b0 = *((const bf16x8*)&Wt[( 0 + l15) * 40 + q * 8]);
    bf16x8 b1 = *((const bf16x8*)&Wt[(16 + l15) * 40 + q * 8]);
    bf16x8 b2 = *((const bf16x8*)&Wt[(32 + l15) * 40 + q * 8]);
    bf16x8 b3 = *((const bf16x8*)&Wt[(48 + l15) * 40 + q * 8]);
    acc0 = __builtin_amdgcn_mfma_f32_16x16x32_bf16(a, b0, acc0, 0, 0, 0);
    acc1 = __builtin_amdgcn_mfma_f32_16x16x32_bf16(a, b1, acc1, 0, 0, 0);
    acc2 = __builtin_amdgcn_mfma_f32_16x16x32_bf16(a, b2, acc2, 0, 0, 0);
    acc3 = __builtin_amdgcn_mfma_f32_16x16x32_bf16(a, b3, acc3, 0, 0, 0);
  }

  // epilogue: x_pw = acc*scale + shift + x  (4 consecutive j per lane per nb)
  const int j = j0 + wv_ * 16 + q * 4;
  #pragma unroll
  for (int nb = 0; nb < 4; ++nb) {
    f32x4 acc = (nb == 0) ? acc0 : (nb == 1) ? acc1 : (nb == 2) ? acc2 : acc3;
    int oo = nb * 16 + l15;
    int o = o0 + oo;
    float s = scaleS[oo], t = shiftS[oo];
    float4 xr = *((const float4*)(xin + bbase + (size_t)o * HW + j));
    ushort4 w4;
    w4.x = f2bf(acc[0] * s + t + xr.x);
    w4.y = f2bf(acc[1] * s + t + xr.y);
    w4.z = f2bf(acc[2] * s + t + xr.z);
    w4.w = f2bf(acc[3] * s + t + xr.w);
    // stash bf16 x_pw in 2nd half of this plane's f32 output slot
    size_t pidx = (size_t)(b * CC + o) * SLOT_U + HALF_U + j;
    *((ushort4*)(xpw + pidx)) = w4;     // 8B aligned (j % 4 == 0)
  }
}

// ---------------------------------------------------------------------------
// Kernel B: 13x13 depthwise conv (SAME, zero pad) + BN_k + (x_pw*dw1)*BN_1
// + exact GELU. One block per (b,c) 56x56 plane; 68x68 fp32 halo in LDS.
// Reads its own plane's bf16 stash (2nd half of slot), syncs, overwrites its
// own full slot with f32 output. No cross-block overlap.
// ---------------------------------------------------------------------------
__global__ __launch_bounds__(256) void dw_conv_bn_gelu(
    float* __restrict__ outf,                 // d_out as f32
    const unsigned short* __restrict__ stash, // d_out as ushort (bf16 halves)
    const float* __restrict__ dwkw,
    const float* __restrict__ dkg, const float* __restrict__ dkb,
    const float* __restrict__ dkm, const float* __restrict__ dkv,
    const float* __restrict__ d1w,
    const float* __restrict__ d1g, const float* __restrict__ d1b,
    const float* __restrict__ d1m, const float* __restrict__ d1v)
{
  __shared__ float tile[68 * 68];
  __shared__ float wl[169];

  const int bc = blockIdx.x;
  const int c = bc % CC;
  const size_t plane_u = (size_t)bc * SLOT_U + HALF_U;  // bf16 stash base
  const size_t plane_f = (size_t)bc * HW;               // f32 out base
  const int tid = threadIdx.x;

  for (int i = tid; i < 169; i += 256) wl[i] = dwkw[c * 169 + i];

  for (int i = tid; i < 68 * 68; i += 256) {
    int ly = i / 68, lx = i % 68;
    int gy = ly - 6, gx = lx - 6;
    float v = 0.f;
    if ((unsigned)gy < (unsigned)WIDTH && (unsigned)gx < (unsigned)WIDTH)
      v = bf2f(stash[plane_u + gy * WIDTH + gx]);
    tile[i] = v;
  }

  const float sk = dkg[c] * rsqrtf(dkv[c] + EPS);
  const float tk = dkb[c] - dkm[c] * sk;
  const float s1 = d1g[c] * rsqrtf(d1v[c] + EPS);
  const float a1 = d1w[c] * s1;
  const float t1 = d1b[c] - d1m[c] * s1;
  const float tsum = tk + t1;

  __syncthreads();   // all reads of this plane's stash complete before writes

  for (int s = tid; s < 784; s += 256) {   // 56 rows * 14 quads
    const int y  = s / 14;
    const int x0 = (s % 14) * 4;
    float acc0 = 0.f, acc1 = 0.f, acc2 = 0.f, acc3 = 0.f;
    #pragma unroll
    for (int ky = 0; ky < 13; ++ky) {
      const float* row = &tile[(y + ky) * 68 + x0];
      float4 A  = *((const float4*)(row));
      float4 Bv = *((const float4*)(row + 4));
      float4 Cv = *((const float4*)(row + 8));
      float4 Dv = *((const float4*)(row + 12));
      float xv[16] = {A.x, A.y, A.z, A.w, Bv.x, Bv.y, Bv.z, Bv.w,
                      Cv.x, Cv.y, Cv.z, Cv.w, Dv.x, Dv.y, Dv.z, Dv.w};
      const float* wr = &wl[ky * 13];
      #pragma unroll
      for (int kx = 0; kx < 13; ++kx) {
        float wv = wr[kx];
        acc0 += wv * xv[kx + 0];
        acc1 += wv * xv[kx + 1];
        acc2 += wv * xv[kx + 2];
        acc3 += wv * xv[kx + 3];
      }
    }
    const float* cr = &tile[(y + 6) * 68 + x0 + 6];
    float v0 = acc0 * sk + tsum + cr[0] * a1;
    float v1 = acc1 * sk + tsum + cr[1] * a1;
    float v2 = acc2 * sk + tsum + cr[2] * a1;
    float v3 = acc3 * sk + tsum + cr[3] * a1;
    // exact GELU: 0.5*v*(1+erf(v/sqrt(2)))
    float4 g4;
    g4.x = 0.5f * v0 * (1.f + erff(v0 * 0.70710678118654752f));
    g4.y = 0.5f * v1 * (1.f + erff(v1 * 0.70710678118654752f));
    g4.z = 0.5f * v2 * (1.f + erff(v2 * 0.70710678118654752f));
    g4.w = 0.5f * v3 * (1.f + erff(v3 * 0.70710678118654752f));
    *((float4*)&outf[plane_f + y * WIDTH + x0]) = g4;
  }
}

extern "C" void kernel_launch(void* const* d_in, const int* in_sizes, int n_in,
                              void* d_out, int out_size, void* d_ws, size_t ws_size,
                              hipStream_t stream) {
  const float* x     = (const float*)d_in[0];
  const float* pw_w  = (const float*)d_in[1];
  const float* pw_g  = (const float*)d_in[2];
  const float* pw_b  = (const float*)d_in[3];
  const float* pw_m  = (const float*)d_in[4];
  const float* pw_v  = (const float*)d_in[5];
  const float* dwk_w = (const float*)d_in[6];
  const float* dwk_g = (const float*)d_in[7];
  const float* dwk_b = (const float*)d_in[8];
  const float* dwk_m = (const float*)d_in[9];
  const float* dwk_v = (const float*)d_in[10];
  const float* dw1_w = (const float*)d_in[11];
  const float* dw1_g = (const float*)d_in[12];
  const float* dw1_b = (const float*)d_in[13];
  const float* dw1_m = (const float*)d_in[14];
  const float* dw1_v = (const float*)d_in[15];
  float* outf = (float*)d_out;
  unsigned short* outu = (unsigned short*)d_out;

  dim3 gridA(HW / 64, CC / 64, 16);
  pw_gemm_bn_res<<<gridA, 256, 0, stream>>>(x, pw_w, pw_g, pw_b, pw_m, pw_v, outu);

  dim3 gridB(16 * CC);
  dw_conv_bn_gelu<<<gridB, 256, 0, stream>>>(outf, outu, dwk_w,
      dwk_g, dwk_b, dwk_m, dwk_v, dw1_w, dw1_g, dw1_b, dw1_m, dw1_v);
}

// Round 5
// 306.557 us; speedup vs baseline: 2.2330x; 2.2330x over previous
//
#include <hip/hip_runtime.h>

#define CC 384
#define HW 3136            // 56*56
#define WIDTH 56
#define PLANE_ELEMS (CC*HW)  // 1204224
#define EPS 1e-5f

// bf16 x_pw for plane p lives in the 2nd half of plane p's f32 output slot:
// ushort index = p*6272 + 3136 + j   (slot = 12544 B = 6272 ushorts)
#define SLOT_U 6272
#define HALF_U 3136

typedef __attribute__((ext_vector_type(8))) short bf16x8;
typedef __attribute__((ext_vector_type(4))) float f32x4;

static __device__ __forceinline__ float bf2f(unsigned short u) {
  union { unsigned int i; float f; } x; x.i = ((unsigned int)u) << 16; return x.f;
}
static __device__ __forceinline__ unsigned short f2bf(float f) {
  union { float f; unsigned int i; } x; x.f = f;
  unsigned int r = x.i + 0x7fffu + ((x.i >> 16) & 1u);
  return (unsigned short)(r >> 16);
}

// ---------------------------------------------------------------------------
// Kernel A: y = W @ x (1x1 conv over channels, f32 in), BN, + residual ->
// x_pw (bf16) stashed into per-plane second-half slots of d_out. (unchanged)
// ---------------------------------------------------------------------------
__global__ __launch_bounds__(256) void pw_gemm_bn_res(
    const float* __restrict__ xin,
    const float* __restrict__ wmat,
    const float* __restrict__ pwg, const float* __restrict__ pwb,
    const float* __restrict__ pwm, const float* __restrict__ pwv,
    unsigned short* __restrict__ xpw)   // = (ushort*)d_out
{
  __shared__ __align__(16) unsigned short Xt[64 * 40];  // [j][k], row padded to 40
  __shared__ __align__(16) unsigned short Wt[64 * 40];  // [n][k]
  __shared__ float scaleS[64];
  __shared__ float shiftS[64];

  const int tid = threadIdx.x;
  const int j0 = blockIdx.x * 64;   // spatial tile (3136 = 49*64)
  const int o0 = blockIdx.y * 64;   // out-channel tile (384 = 6*64)
  const int b  = blockIdx.z;
  const size_t bbase = (size_t)b * PLANE_ELEMS;

  if (tid < 64) {
    int o = o0 + tid;
    float s = pwg[o] * rsqrtf(pwv[o] + EPS);
    scaleS[tid] = s;
    shiftS[tid] = pwb[o] - pwm[o] * s;
  }

  f32x4 acc0 = {0.f,0.f,0.f,0.f}, acc1 = {0.f,0.f,0.f,0.f};
  f32x4 acc2 = {0.f,0.f,0.f,0.f}, acc3 = {0.f,0.f,0.f,0.f};

  const int lane = tid & 63;
  const int wv_  = tid >> 6;        // wave id 0..3 -> spatial sub-tile
  const int l15  = lane & 15;
  const int q    = lane >> 4;

  const int skk  = tid >> 3;          // 0..31  X: k row
  const int sjj  = (tid & 7) << 3;    // 0..56  X: j col start (8 wide)
  const int sn   = tid >> 2;          // 0..63  W: n row
  const int skk0 = (tid & 3) << 3;    // 0..24  W: k start (8 wide)

  for (int kt = 0; kt < 12; ++kt) {
    const int c0 = kt * 32;
    __syncthreads();
    {
      const float* src = xin + bbase + (size_t)(c0 + skk) * HW + (j0 + sjj);
      float4 p0 = *((const float4*)src);
      float4 p1 = *((const float4*)(src + 4));
      Xt[(sjj + 0) * 40 + skk] = f2bf(p0.x);
      Xt[(sjj + 1) * 40 + skk] = f2bf(p0.y);
      Xt[(sjj + 2) * 40 + skk] = f2bf(p0.z);
      Xt[(sjj + 3) * 40 + skk] = f2bf(p0.w);
      Xt[(sjj + 4) * 40 + skk] = f2bf(p1.x);
      Xt[(sjj + 5) * 40 + skk] = f2bf(p1.y);
      Xt[(sjj + 6) * 40 + skk] = f2bf(p1.z);
      Xt[(sjj + 7) * 40 + skk] = f2bf(p1.w);
    }
    {
      const float* src = wmat + (size_t)(o0 + sn) * CC + (c0 + skk0);
      float4 p0 = *((const float4*)src);
      float4 p1 = *((const float4*)(src + 4));
      ushort4 u0, u1;
      u0.x = f2bf(p0.x); u0.y = f2bf(p0.y); u0.z = f2bf(p0.z); u0.w = f2bf(p0.w);
      u1.x = f2bf(p1.x); u1.y = f2bf(p1.y); u1.z = f2bf(p1.z); u1.w = f2bf(p1.w);
      *((ushort4*)&Wt[sn * 40 + skk0])     = u0;
      *((ushort4*)&Wt[sn * 40 + skk0 + 4]) = u1;
    }
    __syncthreads();

    bf16x8 a  = *((const bf16x8*)&Xt[(wv_ * 16 + l15) * 40 + q * 8]);
    bf16x8 b0 = *((const bf16x8*)&Wt[( 0 + l15) * 40 + q * 8]);
    bf16x8 b1 = *((const bf16x8*)&Wt[(16 + l15) * 40 + q * 8]);
    bf16x8 b2 = *((const bf16x8*)&Wt[(32 + l15) * 40 + q * 8]);
    bf16x8 b3 = *((const bf16x8*)&Wt[(48 + l15) * 40 + q * 8]);
    acc0 = __builtin_amdgcn_mfma_f32_16x16x32_bf16(a, b0, acc0, 0, 0, 0);
    acc1 = __builtin_amdgcn_mfma_f32_16x16x32_bf16(a, b1, acc1, 0, 0, 0);
    acc2 = __builtin_amdgcn_mfma_f32_16x16x32_bf16(a, b2, acc2, 0, 0, 0);
    acc3 = __builtin_amdgcn_mfma_f32_16x16x32_bf16(a, b3, acc3, 0, 0, 0);
  }

  const int j = j0 + wv_ * 16 + q * 4;
  #pragma unroll
  for (int nb = 0; nb < 4; ++nb) {
    f32x4 acc = (nb == 0) ? acc0 : (nb == 1) ? acc1 : (nb == 2) ? acc2 : acc3;
    int oo = nb * 16 + l15;
    int o = o0 + oo;
    float s = scaleS[oo], t = shiftS[oo];
    float4 xr = *((const float4*)(xin + bbase + (size_t)o * HW + j));
    ushort4 w4;
    w4.x = f2bf(acc[0] * s + t + xr.x);
    w4.y = f2bf(acc[1] * s + t + xr.y);
    w4.z = f2bf(acc[2] * s + t + xr.z);
    w4.w = f2bf(acc[3] * s + t + xr.w);
    size_t pidx = (size_t)(b * CC + o) * SLOT_U + HALF_U + j;
    *((ushort4*)(xpw + pidx)) = w4;
  }
}

// ---------------------------------------------------------------------------
// Kernel B (MFMA Toeplitz): 13x13 depthwise conv + BN_k + center-tap branch
// + exact GELU, one block per (b,c) plane.
//   out[y][x] = sum_ky sum_k tile[y0+m+ky][x0+k] * w[ky][k-n]   (m,n in 16x16)
// => per 16x16 output tile: 13 accumulating mfma_f32_16x16x32_bf16.
// B_ky[n][k] = w[ky][k-n] built once per block (channel-constant), hoisted
// into 52 VGPRs/wave. Tile: 76 x 88 bf16, zero-padded (halo + edge-tile
// overreach) so no garbage enters any fragment. Stride 88: rows 16B-aligned
// for ds_read_b128; bank pattern 12m mod 32 -> worst 2-way (free).
// ---------------------------------------------------------------------------
#define TSTRIDE 88
#define TROWS 76

__global__ __launch_bounds__(256) void dw_conv_mfma(
    float* __restrict__ outf,                 // d_out as f32
    const unsigned short* __restrict__ stash, // d_out as ushort (bf16 halves)
    const float* __restrict__ dwkw,
    const float* __restrict__ dkg, const float* __restrict__ dkb,
    const float* __restrict__ dkm, const float* __restrict__ dkv,
    const float* __restrict__ d1w,
    const float* __restrict__ d1g, const float* __restrict__ d1b,
    const float* __restrict__ d1m, const float* __restrict__ d1v)
{
  __shared__ __align__(16) unsigned short tile[TROWS * TSTRIDE]; // 13376 B
  __shared__ __align__(16) unsigned short Bt[13 * 16 * 32];      // 13312 B

  const int bc = blockIdx.x;
  const int c = bc % CC;
  const size_t plane_u = (size_t)bc * SLOT_U + HALF_U;  // bf16 stash base
  const size_t plane_f = (size_t)bc * HW;               // f32 out base
  const int tid = threadIdx.x;

  // stage plane into zero-padded bf16 tile (halo 6; extra rows/cols zeroed)
  for (int i = tid; i < TROWS * TSTRIDE; i += 256) {
    int r = i / TSTRIDE, col = i - r * TSTRIDE;
    int gy = r - 6, gx = col - 6;
    unsigned short v = 0;
    if ((unsigned)gy < (unsigned)WIDTH && (unsigned)gx < (unsigned)WIDTH)
      v = stash[plane_u + gy * WIDTH + gx];
    tile[i] = v;
  }
  // build Toeplitz B: Bt[ky][n][k] = w[ky][k-n] (0 if k-n outside [0,13))
  for (int i = tid; i < 13 * 512; i += 256) {
    int ky = i >> 9, rem = i & 511, n = rem >> 5, k = rem & 31;
    int kx = k - n;
    float wv = ((unsigned)kx < 13u) ? dwkw[c * 169 + ky * 13 + kx] : 0.f;
    Bt[i] = f2bf(wv);
  }

  const float sk = dkg[c] * rsqrtf(dkv[c] + EPS);
  const float tk = dkb[c] - dkm[c] * sk;
  const float s1 = d1g[c] * rsqrtf(d1v[c] + EPS);
  const float a1 = d1w[c] * s1;
  const float t1 = d1b[c] - d1m[c] * s1;
  const float tsum = tk + t1;

  __syncthreads();

  const int lane = tid & 63;
  const int l15  = lane & 15;   // A: m index / D: col (x offset)
  const int q    = lane >> 4;   // A/B: k quad / D: row group
  const int wid  = tid >> 6;

  // hoist B fragments (channel-constant) into registers
  bf16x8 bfr[13];
  #pragma unroll
  for (int ky = 0; ky < 13; ++ky)
    bfr[ky] = *((const bf16x8*)&Bt[(ky * 16 + l15) * 32 + q * 8]);

  // 16 output tiles of 16x16 cover 64x64 >= 56x56; 4 waves -> 4 tiles each
  for (int t = wid; t < 16; t += 4) {
    const int y0 = (t >> 2) * 16, x0 = (t & 3) * 16;
    f32x4 acc = {0.f, 0.f, 0.f, 0.f};
    #pragma unroll
    for (int ky = 0; ky < 13; ++ky) {
      bf16x8 a = *((const bf16x8*)&tile[(y0 + l15 + ky) * TSTRIDE + x0 + q * 8]);
      acc = __builtin_amdgcn_mfma_f32_16x16x32_bf16(a, bfr[ky], acc, 0, 0, 0);
    }
    // epilogue: D row m = q*4+r, col n = l15
    const int x = x0 + l15;
    if (x < WIDTH) {
      #pragma unroll
      for (int r = 0; r < 4; ++r) {
        const int y = y0 + q * 4 + r;
        if (y < WIDTH) {
          float ctr = bf2f(tile[(y + 6) * TSTRIDE + x + 6]);
          float v = acc[r] * sk + tsum + ctr * a1;
          outf[plane_f + y * WIDTH + x] =
              0.5f * v * (1.f + erff(v * 0.70710678118654752f));
        }
      }
    }
  }
}

extern "C" void kernel_launch(void* const* d_in, const int* in_sizes, int n_in,
                              void* d_out, int out_size, void* d_ws, size_t ws_size,
                              hipStream_t stream) {
  const float* x     = (const float*)d_in[0];
  const float* pw_w  = (const float*)d_in[1];
  const float* pw_g  = (const float*)d_in[2];
  const float* pw_b  = (const float*)d_in[3];
  const float* pw_m  = (const float*)d_in[4];
  const float* pw_v  = (const float*)d_in[5];
  const float* dwk_w = (const float*)d_in[6];
  const float* dwk_g = (const float*)d_in[7];
  const float* dwk_b = (const float*)d_in[8];
  const float* dwk_m = (const float*)d_in[9];
  const float* dwk_v = (const float*)d_in[10];
  const float* dw1_w = (const float*)d_in[11];
  const float* dw1_g = (const float*)d_in[12];
  const float* dw1_b = (const float*)d_in[13];
  const float* dw1_m = (const float*)d_in[14];
  const float* dw1_v = (const float*)d_in[15];
  float* outf = (float*)d_out;
  unsigned short* outu = (unsigned short*)d_out;

  dim3 gridA(HW / 64, CC / 64, 16);
  pw_gemm_bn_res<<<gridA, 256, 0, stream>>>(x, pw_w, pw_g, pw_b, pw_m, pw_v, outu);

  dim3 gridB(16 * CC);
  dw_conv_mfma<<<gridB, 256, 0, stream>>>(outf, outu, dwk_w,
      dwk_g, dwk_b, dwk_m, dwk_v, dw1_w, dw1_g, dw1_b, dw1_m, dw1_v);
}